// Round 2
// 850.993 us; speedup vs baseline: 1.0135x; 1.0135x over previous
//
#include <hip/hip_runtime.h>
#include <hip/hip_bf16.h>

#define B_SAMP 16384
#define NFEAT 26
#define VOCAB 100000
#define DIM 64
#define NDENSE 13
#define H1 1024
#define H2 512
#define H3 256
#define KIN ((NFEAT + 1) * DIM)   // 1728
#define KP1 1792                  // KIN padded to multiple of 128

typedef int   i32x4 __attribute__((ext_vector_type(4)));
typedef int   i32x8 __attribute__((ext_vector_type(8)));
typedef float f32x4 __attribute__((ext_vector_type(4)));

// ---------------------------------------------------------------- helpers
__device__ inline void async_load16(const void* g, void* lds) {
  __builtin_amdgcn_global_load_lds(
      (const __attribute__((address_space(1))) void*)g,
      (__attribute__((address_space(3))) void*)lds, 16, 0, 0);
}

__device__ inline unsigned char f32_to_fp8(float v) {
  // gfx950: OCP e4m3fn, RNE, denorm-capable HW convert
  return (unsigned char)(__builtin_amdgcn_cvt_pk_fp8_f32(v, v, 0, false) & 0xff);
}

// ------------------------------------------------- embedding + FM + first
// one wave per sample; lane = embedding dim d (D=64 exactly one wave)
// also initializes out[b] = bias + first + second (deep part atomically
// accumulated later by the reducing GEMM3)
__global__ __launch_bounds__(256) void k_embed_fm(
    const float* __restrict__ dense, const int* __restrict__ sidx,
    const float* __restrict__ emb, const float* __restrict__ lin,
    const float* __restrict__ Wd, const float* __restrict__ Wld,
    const float* __restrict__ bld, const float* __restrict__ bias,
    unsigned char* __restrict__ h, float* __restrict__ out)
{
  int wave = threadIdx.x >> 6, lane = threadIdx.x & 63;
  int b = blockIdx.x * 4 + wave;
  const float* drow = dense + b * NDENSE;

  float de = 0.f;
#pragma unroll
  for (int nd = 0; nd < NDENSE; ++nd) de += drow[nd] * Wd[nd * DIM + lane];

  unsigned char* hrow = h + (size_t)b * KP1;
  hrow[lane] = f32_to_fp8(de);
  hrow[KIN + lane] = 0;                    // zero the 64-col K pad
  float sum_e = de, sumsq = de * de;

  float fo = 0.f;
  if (lane < NDENSE) fo = drow[lane] * Wld[lane];

  const int* irow = sidx + b * NFEAT;
#pragma unroll
  for (int f = 0; f < NFEAT; ++f) {
    int ix = irow[f];                                      // broadcast load
    float e = emb[((size_t)f * VOCAB + ix) * DIM + lane];  // coalesced 256B row
    sum_e += e; sumsq += e * e;
    hrow[(f + 1) * DIM + lane] = f32_to_fp8(e);
  }
  if (lane < NFEAT) fo += lin[(size_t)lane * VOCAB + irow[lane]];

  float sec = sum_e * sum_e - sumsq;
#pragma unroll
  for (int o = 32; o > 0; o >>= 1) {
    sec += __shfl_down(sec, o);
    fo  += __shfl_down(fo, o);
  }
  if (lane == 0) out[b] = fo + bld[0] + 0.5f * sec + bias[0];
}

// --------------- fused weight prep: fp32 [R][C] -> fp8 [C][Rp], pad r>=R
// one launch covering W1 (1792 blocks), W2 (512), W3 (128) = 2432 blocks
__global__ __launch_bounds__(256) void k_prep_weights(
    const float* __restrict__ W1, const float* __restrict__ W2,
    const float* __restrict__ W3,
    unsigned char* __restrict__ W1t, unsigned char* __restrict__ W2t,
    unsigned char* __restrict__ W3t)
{
  __shared__ float tile[32][33];
  int id = blockIdx.x;
  const float* src; unsigned char* dst; int R, C, Rp, bx, by;
  if (id < 1792)      { src = W1; dst = W1t; R = KIN; C = H1; Rp = KP1; bx = id % 32; by = id / 32; }
  else if (id < 2304) { id -= 1792; src = W2; dst = W2t; R = H1; C = H2; Rp = H1; bx = id % 16; by = id / 16; }
  else                { id -= 2304; src = W3; dst = W3t; R = H2; C = H3; Rp = H2; bx = id % 8;  by = id / 8;  }
  int c0 = bx * 32, r0 = by * 32;
  int tx = threadIdx.x & 31, ty = threadIdx.x >> 5;   // 32 x 8
#pragma unroll
  for (int i = 0; i < 32; i += 8) {
    int r = r0 + ty + i;
    tile[ty + i][tx] = (r < R) ? src[(size_t)r * C + c0 + tx] : 0.f;
  }
  __syncthreads();
#pragma unroll
  for (int i = 0; i < 32; i += 8)
    dst[(size_t)(c0 + ty + i) * Rp + r0 + tx] = f32_to_fp8(tile[tx][ty + i]);
}

// ----------------------------------------------------- MX-fp8 GEMM (scale=1)
// C[M][N] = A[M][K] * Bt[N][K]^T, fp8 e4m3 in, fp32 accum, K%128==0.
// 128x128 block tile, BK=128, 4 waves 2x2, 4x4 of 16x16x128 MFMAs per wave.
// XCD-bijective swizzle: each XCD walks N-blocks fastest => A-panel stays
// L2-resident and is reused across all N-blocks on that XCD.
// REDUCE variant (last layer): relu(C) . wo row-reduced, atomicAdd into out.
template <bool RELU, bool FP8OUT, bool REDUCE>
__global__ __launch_bounds__(256) void k_gemm_fp8(
    const unsigned char* __restrict__ A,
    const unsigned char* __restrict__ Bt,
    void* __restrict__ Cv, int M, int N, int K,
    const float* __restrict__ wo, float* __restrict__ outp)
{
  __shared__ unsigned char As[16384];
  __shared__ unsigned char Bs[16384];
  int tid = threadIdx.x;
  int wave = tid >> 6, lane = tid & 63;
  int wm = wave & 1, wn = wave >> 1;

  // bijective XCD swizzle (all grids have nwg % 8 == 0)
  int gx = gridDim.x, gy = gridDim.y;
  int wg = blockIdx.y * gx + blockIdx.x;
  int cpx = (gx * gy) >> 3;
  int swz = (wg & 7) * cpx + (wg >> 3);
  int bm = (swz / gy) * 128, bn = (swz % gy) * 128;

  int l15 = lane & 15, quad = lane >> 4;

  f32x4 acc[4][4];
#pragma unroll
  for (int i = 0; i < 4; ++i)
#pragma unroll
    for (int j = 0; j < 4; ++j) acc[i][j] = (f32x4){0.f, 0.f, 0.f, 0.f};

  int nk = K >> 7;
  for (int kt = 0; kt < nk; ++kt) {
    int k0 = kt << 7;
    __syncthreads();
#pragma unroll
    for (int s = 0; s < 2; ++s) {
      int st = 2 * wave + s;                                // subtile 0..7
      size_t ga = (size_t)(bm + st * 16 + l15) * K + k0 + quad * 32;
      size_t gb = (size_t)(bn + st * 16 + l15) * K + k0 + quad * 32;
#pragma unroll
      for (int j = 0; j < 2; ++j) {
        async_load16(A + ga + j * 16, &As[st * 2048 + j * 1024]);
        async_load16(Bt + gb + j * 16, &Bs[st * 2048 + j * 1024]);
      }
    }
    __syncthreads();

    i32x8 af[4], bf[4];
#pragma unroll
    for (int i = 0; i < 4; ++i) {
      {
        i32x4 lo = *(const i32x4*)&As[(4 * wm + i) * 2048 + lane * 16];
        i32x4 hi = *(const i32x4*)&As[(4 * wm + i) * 2048 + 1024 + lane * 16];
        af[i] = (i32x8){lo.x, lo.y, lo.z, lo.w, hi.x, hi.y, hi.z, hi.w};
      }
      {
        i32x4 lo = *(const i32x4*)&Bs[(4 * wn + i) * 2048 + lane * 16];
        i32x4 hi = *(const i32x4*)&Bs[(4 * wn + i) * 2048 + 1024 + lane * 16];
        bf[i] = (i32x8){lo.x, lo.y, lo.z, lo.w, hi.x, hi.y, hi.z, hi.w};
      }
    }
#pragma unroll
    for (int mi = 0; mi < 4; ++mi)
#pragma unroll
      for (int ni = 0; ni < 4; ++ni)
        acc[mi][ni] = __builtin_amdgcn_mfma_scale_f32_16x16x128_f8f6f4(
            af[mi], bf[ni], acc[mi][ni],
            0 /*fp8 A*/, 0 /*fp8 B*/, 0, 0x7f7f7f7f, 0, 0x7f7f7f7f);
  }

  // epilogue: C/D layout (shape-determined): col = lane&15, row = quad*4 + r
  if (REDUCE) {
    // out[m] += sum_n relu(C[m][n]) * wo[n]
    float wv[4];
#pragma unroll
    for (int ni = 0; ni < 4; ++ni) wv[ni] = wo[bn + 64 * wn + 16 * ni + l15];
#pragma unroll
    for (int mi = 0; mi < 4; ++mi)
#pragma unroll
      for (int r = 0; r < 4; ++r) {
        float s = 0.f;
#pragma unroll
        for (int ni = 0; ni < 4; ++ni)
          s += fmaxf(acc[mi][ni][r], 0.f) * wv[ni];
        // reduce across the 16 lanes of this quad (l15 bits only)
        s += __shfl_xor(s, 1);
        s += __shfl_xor(s, 2);
        s += __shfl_xor(s, 4);
        s += __shfl_xor(s, 8);
        if (l15 == 0)
          atomicAdd(outp + bm + 64 * wm + 16 * mi + quad * 4 + r, s);
      }
  } else {
#pragma unroll
    for (int mi = 0; mi < 4; ++mi)
#pragma unroll
      for (int ni = 0; ni < 4; ++ni)
#pragma unroll
        for (int r = 0; r < 4; ++r) {
          int m = bm + 64 * wm + 16 * mi + quad * 4 + r;
          int n = bn + 64 * wn + 16 * ni + l15;
          float v = acc[mi][ni][r];
          if (RELU) v = fmaxf(v, 0.f);
          if (FP8OUT) ((unsigned char*)Cv)[(size_t)m * N + n] = f32_to_fp8(v);
          else        ((float*)Cv)[(size_t)m * N + n] = v;
        }
  }
}

// ---------------------------------------------------------------------------
extern "C" void kernel_launch(void* const* d_in, const int* in_sizes, int n_in,
                              void* d_out, int out_size, void* d_ws, size_t ws_size,
                              hipStream_t stream) {
  const float* dense = (const float*)d_in[0];
  const int*   sidx  = (const int*)d_in[1];
  const float* bias  = (const float*)d_in[2];
  const float* emb   = (const float*)d_in[3];
  const float* lin   = (const float*)d_in[4];
  const float* Wd    = (const float*)d_in[5];
  const float* Wld   = (const float*)d_in[6];
  const float* bld   = (const float*)d_in[7];
  const float* W1    = (const float*)d_in[8];
  const float* W2    = (const float*)d_in[9];
  const float* W3    = (const float*)d_in[10];
  const float* Wout  = (const float*)d_in[11];
  float* out = (float*)d_out;

  char* ws = (char*)d_ws;
  const size_t o_h   = 0;                      // B*1792   = 29,360,128
  const size_t o_a1  = 29360128;               // B*1024   = 16,777,216
  const size_t o_a2  = 46137344;               // B*512    =  8,388,608
  const size_t o_w1t = 54525952;               // 1024*1792 = 1,835,008
  const size_t o_w2t = 56360960;               // 512*1024  =   524,288
  const size_t o_w3t = 56885248;               // 256*512   =   131,072

  unsigned char* h   = (unsigned char*)(ws + o_h);
  unsigned char* a1  = (unsigned char*)(ws + o_a1);
  unsigned char* a2  = (unsigned char*)(ws + o_a2);
  unsigned char* W1t = (unsigned char*)(ws + o_w1t);
  unsigned char* W2t = (unsigned char*)(ws + o_w2t);
  unsigned char* W3t = (unsigned char*)(ws + o_w3t);

  // weight prep: fp32 [K][N] -> fp8 [N][Kp], single fused launch
  k_prep_weights<<<2432, 256, 0, stream>>>(W1, W2, W3, W1t, W2t, W3t);

  // gather + FM + first-order + fp8 h materialization + out init
  k_embed_fm<<<B_SAMP / 4, 256, 0, stream>>>(dense, sidx, emb, lin, Wd, Wld, bld,
                                             bias, h, out);

  // MLP, MX-fp8 MFMA (scales = 1.0); last layer reduces directly into out
  k_gemm_fp8<true, true,  false><<<dim3(B_SAMP / 128, H1 / 128), 256, 0, stream>>>(
      h,  W1t, a1, B_SAMP, H1, KP1, nullptr, nullptr);
  k_gemm_fp8<true, true,  false><<<dim3(B_SAMP / 128, H2 / 128), 256, 0, stream>>>(
      a1, W2t, a2, B_SAMP, H2, H1, nullptr, nullptr);
  k_gemm_fp8<true, false, true ><<<dim3(B_SAMP / 128, H3 / 128), 256, 0, stream>>>(
      a2, W3t, nullptr, B_SAMP, H3, H2, Wout, out);
}

// Round 3
// 848.027 us; speedup vs baseline: 1.0170x; 1.0035x over previous
//
#include <hip/hip_runtime.h>
#include <hip/hip_bf16.h>

#define B_SAMP 16384
#define NFEAT 26
#define VOCAB 100000
#define DIM 64
#define NDENSE 13
#define H1 1024
#define H2 512
#define H3 256
#define KIN ((NFEAT + 1) * DIM)   // 1728
#define KP1 1792                  // KIN padded to multiple of 128

typedef int   i32x4 __attribute__((ext_vector_type(4)));
typedef int   i32x8 __attribute__((ext_vector_type(8)));
typedef float f32x4 __attribute__((ext_vector_type(4)));

// ---------------------------------------------------------------- helpers
__device__ inline void async_load16(const void* g, void* lds) {
  __builtin_amdgcn_global_load_lds(
      (const __attribute__((address_space(1))) void*)g,
      (__attribute__((address_space(3))) void*)lds, 16, 0, 0);
}

__device__ inline unsigned char f32_to_fp8(float v) {
  // gfx950: OCP e4m3fn, RNE, denorm-capable HW convert
  return (unsigned char)(__builtin_amdgcn_cvt_pk_fp8_f32(v, v, 0, false) & 0xff);
}

__device__ inline unsigned int pack_fp8x4(float a, float b, float c, float d) {
  unsigned int r = __builtin_amdgcn_cvt_pk_fp8_f32(a, b, 0u, false);
  r = __builtin_amdgcn_cvt_pk_fp8_f32(c, d, r, true);
  return r;
}

// ---------------- fused: embedding+FM+first (blocks 0..4095, 4 samples each)
//                  + weight transpose fp32->fp8 (blocks 4096..6527)
// Embed wave layout: lane = fg*16 + dq; fg = feature sub-slot (0..3),
// dq = dim quad (dims 4dq..4dq+3). Gathers are float4 (16B/lane, 256B/row),
// h stores are packed fp8 dwords (256B contiguous per 4-feature group).
// FM algebra: S_d accumulated per-lane f32x4 then cross-fg reduced;
// sec = sum_d S_d^2 - Q = 0.25*sum_lanes dot(S4,S4) - sum_lanes q.
__global__ __launch_bounds__(256) void k_embed_prep(
    const float* __restrict__ dense, const int* __restrict__ sidx,
    const float* __restrict__ emb, const float* __restrict__ lin,
    const float* __restrict__ Wd, const float* __restrict__ Wld,
    const float* __restrict__ bld, const float* __restrict__ bias,
    unsigned char* __restrict__ h, float* __restrict__ out,
    const float* __restrict__ W1, const float* __restrict__ W2,
    const float* __restrict__ W3,
    unsigned char* __restrict__ W1t, unsigned char* __restrict__ W2t,
    unsigned char* __restrict__ W3t)
{
  __shared__ float tile[32][33];

  if (blockIdx.x >= 4096) {
    // ---------------- weight-prep path: fp32 [R][C] -> fp8 [C][Rp]
    int id = blockIdx.x - 4096;
    const float* src; unsigned char* dst; int R, C, Rp, bx, by;
    if (id < 1792)      { src = W1; dst = W1t; R = KIN; C = H1; Rp = KP1; bx = id % 32; by = id / 32; }
    else if (id < 2304) { id -= 1792; src = W2; dst = W2t; R = H1; C = H2; Rp = H1; bx = id % 16; by = id / 16; }
    else                { id -= 2304; src = W3; dst = W3t; R = H2; C = H3; Rp = H2; bx = id % 8;  by = id / 8;  }
    int c0 = bx * 32, r0 = by * 32;
    int tx = threadIdx.x & 31, ty = threadIdx.x >> 5;   // 32 x 8
#pragma unroll
    for (int i = 0; i < 32; i += 8) {
      int r = r0 + ty + i;
      tile[ty + i][tx] = (r < R) ? src[(size_t)r * C + c0 + tx] : 0.f;
    }
    __syncthreads();
#pragma unroll
    for (int i = 0; i < 32; i += 8)
      dst[(size_t)(c0 + ty + i) * Rp + r0 + tx] = f32_to_fp8(tile[tx][ty + i]);
    return;
  }

  // ---------------- embed path
  int wave = threadIdx.x >> 6, lane = threadIdx.x & 63;
  int b = blockIdx.x * 4 + wave;
  const float* drow = dense + b * NDENSE;
  const int*   irow = sidx + b * NFEAT;
  int fg = lane >> 4;          // feature sub-slot 0..3
  int dq = lane & 15;          // dim quad: dims 4dq..4dq+3

  int myidx = (lane < NFEAT) ? irow[lane] : 0;   // coalesced, loaded once

  // dense embedding for dims 4dq..4dq+3 (redundant across fg, cache-hot)
  float dx = 0.f, dy = 0.f, dz = 0.f, dw = 0.f;
#pragma unroll
  for (int nd = 0; nd < NDENSE; ++nd) {
    float dv = drow[nd];
    const f32x4 w = *(const f32x4*)&Wd[nd * DIM + 4 * dq];
    dx += dv * w.x; dy += dv * w.y; dz += dv * w.z; dw += dv * w.w;
  }

  unsigned char* hrow = h + (size_t)b * KP1;
  float Sx, Sy, Sz, Sw, q;
  if (fg == 0) {
    Sx = dx; Sy = dy; Sz = dz; Sw = dw;
    q = dx * dx + dy * dy + dz * dz + dw * dw;
    *(unsigned int*)&hrow[4 * dq] = pack_fp8x4(dx, dy, dz, dw);
  } else {
    Sx = Sy = Sz = Sw = 0.f; q = 0.f;
  }
  if (fg == 1) *(unsigned int*)&hrow[KIN + 4 * dq] = 0u;   // zero 64B K pad

  float fo = 0.f;
  if (lane < NDENSE) fo = drow[lane] * Wld[lane];
  if (lane < NFEAT)  fo += lin[(size_t)lane * VOCAB + myidx];

  // sparse features, 4 at a time (g=6 is the 2-feature remainder)
#pragma unroll
  for (int g = 0; g < 7; ++g) {
    int f = 4 * g + fg;
    int ix = __shfl(myidx, f & 31);
    if (f < NFEAT) {
      const f32x4 e = *(const f32x4*)(emb + ((size_t)f * VOCAB + ix) * DIM + 4 * dq);
      Sx += e.x; Sy += e.y; Sz += e.z; Sw += e.w;
      q += e.x * e.x + e.y * e.y + e.z * e.z + e.w * e.w;
      *(unsigned int*)&hrow[(f + 1) * DIM + 4 * dq] = pack_fp8x4(e.x, e.y, e.z, e.w);
    }
  }

  // reduce S across the 4 fg groups (lanes dq, dq+16, dq+32, dq+48)
#pragma unroll
  for (int off = 16; off < 64; off <<= 1) {
    Sx += __shfl_xor(Sx, off);
    Sy += __shfl_xor(Sy, off);
    Sz += __shfl_xor(Sz, off);
    Sw += __shfl_xor(Sw, off);
  }
  // sec = sum_d S_d^2 - Q = 0.25 * sum_lanes dot(S,S) - sum_lanes q
  float u = 0.25f * (Sx * Sx + Sy * Sy + Sz * Sz + Sw * Sw) - q;
#pragma unroll
  for (int o = 32; o > 0; o >>= 1) {
    u  += __shfl_down(u, o);
    fo += __shfl_down(fo, o);
  }
  if (lane == 0) out[b] = fo + bld[0] + 0.5f * u + bias[0];
}

// ----------------------------------------------------- MX-fp8 GEMM (scale=1)
// C[M][N] = A[M][K] * Bt[N][K]^T, fp8 e4m3 in, fp32 accum, K%128==0.
// 128x128 block tile, BK=128, 4 waves 2x2, 4x4 of 16x16x128 MFMAs per wave.
// XCD-bijective swizzle: each XCD walks N-blocks fastest => A-panel stays
// L2-resident and is reused across all N-blocks on that XCD.
// REDUCE variant (last layer): relu(C) . wo row-reduced, atomicAdd into out.
template <bool RELU, bool FP8OUT, bool REDUCE>
__global__ __launch_bounds__(256) void k_gemm_fp8(
    const unsigned char* __restrict__ A,
    const unsigned char* __restrict__ Bt,
    void* __restrict__ Cv, int M, int N, int K,
    const float* __restrict__ wo, float* __restrict__ outp)
{
  __shared__ unsigned char As[16384];
  __shared__ unsigned char Bs[16384];
  int tid = threadIdx.x;
  int wave = tid >> 6, lane = tid & 63;
  int wm = wave & 1, wn = wave >> 1;

  // bijective XCD swizzle (all grids have nwg % 8 == 0)
  int gx = gridDim.x, gy = gridDim.y;
  int wg = blockIdx.y * gx + blockIdx.x;
  int cpx = (gx * gy) >> 3;
  int swz = (wg & 7) * cpx + (wg >> 3);
  int bm = (swz / gy) * 128, bn = (swz % gy) * 128;

  int l15 = lane & 15, quad = lane >> 4;

  f32x4 acc[4][4];
#pragma unroll
  for (int i = 0; i < 4; ++i)
#pragma unroll
    for (int j = 0; j < 4; ++j) acc[i][j] = (f32x4){0.f, 0.f, 0.f, 0.f};

  int nk = K >> 7;
  for (int kt = 0; kt < nk; ++kt) {
    int k0 = kt << 7;
    __syncthreads();
#pragma unroll
    for (int s = 0; s < 2; ++s) {
      int st = 2 * wave + s;                                // subtile 0..7
      size_t ga = (size_t)(bm + st * 16 + l15) * K + k0 + quad * 32;
      size_t gb = (size_t)(bn + st * 16 + l15) * K + k0 + quad * 32;
#pragma unroll
      for (int j = 0; j < 2; ++j) {
        async_load16(A + ga + j * 16, &As[st * 2048 + j * 1024]);
        async_load16(Bt + gb + j * 16, &Bs[st * 2048 + j * 1024]);
      }
    }
    __syncthreads();

    i32x8 af[4], bf[4];
#pragma unroll
    for (int i = 0; i < 4; ++i) {
      {
        i32x4 lo = *(const i32x4*)&As[(4 * wm + i) * 2048 + lane * 16];
        i32x4 hi = *(const i32x4*)&As[(4 * wm + i) * 2048 + 1024 + lane * 16];
        af[i] = (i32x8){lo.x, lo.y, lo.z, lo.w, hi.x, hi.y, hi.z, hi.w};
      }
      {
        i32x4 lo = *(const i32x4*)&Bs[(4 * wn + i) * 2048 + lane * 16];
        i32x4 hi = *(const i32x4*)&Bs[(4 * wn + i) * 2048 + 1024 + lane * 16];
        bf[i] = (i32x8){lo.x, lo.y, lo.z, lo.w, hi.x, hi.y, hi.z, hi.w};
      }
    }
#pragma unroll
    for (int mi = 0; mi < 4; ++mi)
#pragma unroll
      for (int ni = 0; ni < 4; ++ni)
        acc[mi][ni] = __builtin_amdgcn_mfma_scale_f32_16x16x128_f8f6f4(
            af[mi], bf[ni], acc[mi][ni],
            0 /*fp8 A*/, 0 /*fp8 B*/, 0, 0x7f7f7f7f, 0, 0x7f7f7f7f);
  }

  // epilogue: C/D layout (shape-determined): col = lane&15, row = quad*4 + r
  if (REDUCE) {
    // out[m] += sum_n relu(C[m][n]) * wo[n]
    float wv[4];
#pragma unroll
    for (int ni = 0; ni < 4; ++ni) wv[ni] = wo[bn + 64 * wn + 16 * ni + l15];
#pragma unroll
    for (int mi = 0; mi < 4; ++mi)
#pragma unroll
      for (int r = 0; r < 4; ++r) {
        float s = 0.f;
#pragma unroll
        for (int ni = 0; ni < 4; ++ni)
          s += fmaxf(acc[mi][ni][r], 0.f) * wv[ni];
        // reduce across the 16 lanes of this quad (l15 bits only)
        s += __shfl_xor(s, 1);
        s += __shfl_xor(s, 2);
        s += __shfl_xor(s, 4);
        s += __shfl_xor(s, 8);
        if (l15 == 0)
          atomicAdd(outp + bm + 64 * wm + 16 * mi + quad * 4 + r, s);
      }
  } else {
#pragma unroll
    for (int mi = 0; mi < 4; ++mi)
#pragma unroll
      for (int ni = 0; ni < 4; ++ni)
#pragma unroll
        for (int r = 0; r < 4; ++r) {
          int m = bm + 64 * wm + 16 * mi + quad * 4 + r;
          int n = bn + 64 * wn + 16 * ni + l15;
          float v = acc[mi][ni][r];
          if (RELU) v = fmaxf(v, 0.f);
          if (FP8OUT) ((unsigned char*)Cv)[(size_t)m * N + n] = f32_to_fp8(v);
          else        ((float*)Cv)[(size_t)m * N + n] = v;
        }
  }
}

// ---------------------------------------------------------------------------
extern "C" void kernel_launch(void* const* d_in, const int* in_sizes, int n_in,
                              void* d_out, int out_size, void* d_ws, size_t ws_size,
                              hipStream_t stream) {
  const float* dense = (const float*)d_in[0];
  const int*   sidx  = (const int*)d_in[1];
  const float* bias  = (const float*)d_in[2];
  const float* emb   = (const float*)d_in[3];
  const float* lin   = (const float*)d_in[4];
  const float* Wd    = (const float*)d_in[5];
  const float* Wld   = (const float*)d_in[6];
  const float* bld   = (const float*)d_in[7];
  const float* W1    = (const float*)d_in[8];
  const float* W2    = (const float*)d_in[9];
  const float* W3    = (const float*)d_in[10];
  const float* Wout  = (const float*)d_in[11];
  float* out = (float*)d_out;

  char* ws = (char*)d_ws;
  const size_t o_h   = 0;                      // B*1792   = 29,360,128
  const size_t o_a1  = 29360128;               // B*1024   = 16,777,216
  const size_t o_a2  = 46137344;               // B*512    =  8,388,608
  const size_t o_w1t = 54525952;               // 1024*1792 = 1,835,008
  const size_t o_w2t = 56360960;               // 512*1024  =   524,288
  const size_t o_w3t = 56885248;               // 256*512   =   131,072

  unsigned char* h   = (unsigned char*)(ws + o_h);
  unsigned char* a1  = (unsigned char*)(ws + o_a1);
  unsigned char* a2  = (unsigned char*)(ws + o_a2);
  unsigned char* W1t = (unsigned char*)(ws + o_w1t);
  unsigned char* W2t = (unsigned char*)(ws + o_w2t);
  unsigned char* W3t = (unsigned char*)(ws + o_w3t);

  // fused: embed+FM+first (4096 blocks) + weight prep (2432 blocks)
  k_embed_prep<<<4096 + 2432, 256, 0, stream>>>(
      dense, sidx, emb, lin, Wd, Wld, bld, bias, h, out,
      W1, W2, W3, W1t, W2t, W3t);

  // MLP, MX-fp8 MFMA (scales = 1.0); last layer reduces directly into out
  k_gemm_fp8<true, true,  false><<<dim3(B_SAMP / 128, H1 / 128), 256, 0, stream>>>(
      h,  W1t, a1, B_SAMP, H1, KP1, nullptr, nullptr);
  k_gemm_fp8<true, true,  false><<<dim3(B_SAMP / 128, H2 / 128), 256, 0, stream>>>(
      a1, W2t, a2, B_SAMP, H2, H1, nullptr, nullptr);
  k_gemm_fp8<true, false, true ><<<dim3(B_SAMP / 128, H3 / 128), 256, 0, stream>>>(
      a2, W3t, nullptr, B_SAMP, H3, H2, Wout, out);
}